// Round 2
// baseline (217.357 us; speedup 1.0000x reference)
//
#include <hip/hip_runtime.h>
#include <hip/hip_bf16.h>

// NT-Xent (B=8192, D=128), top-2 formulation. R10 = R9 (LDS-free ntx_main)
// with workspace held at the proven 9 MiB: pos is not materialized; K1 folds
// -mean(pos) into out via block-reduced atomicAdd (out zeroed by stream-ordered
// hipMemsetAsync before K1 -> no race with K1 atomics).
// B panel per split = 2048x256B = 512 KB -> L2-resident per XCD (grid laid out
// so linear block id % 8 == split -> XCD round-robin pins one panel per XCD).
// Waves read B fragments straight from L2 (16B/lane dwordx4, same fragment
// geometry as the old ds_read path). Removes: barriers, ds_write/ds_read,
// vmcnt(0) drain, staging VALU, 4.19M bank-conflict cycles; occupancy no
// longer LDS-bound. Top-2 of a = sim*log2e/T (exp monotone),
// lse = e1 + log1p(exp(e2-e1)), exact to ~1e-2 << thr.
// K1: pair-normalize zi/zj rows together; emit repsB (unit), repsA (unit*C);
//     pair-dot dj is free here -> pos term accumulated in fp32 (more accurate
//     than the old bf16 K3 gather-dot, and deletes K3's 8 MB read).
// K2: 64 row-blocks(256 rows, 4 waves x 64 rows) x 8 splits; 16 col-tiles of
//     128. Per c8: 4 global bfrag loads -> 16 MFMA -> 3-op top-2 update.
// K3: merge 8 split partials (1 MiB) -> lse -> mean -> atomicAdd.

#define NROWS 16384
#define BHALF 8192
#define DDIM  128
#define TILE  128
#define ROWS_PER_BLOCK 256
#define NSPLIT 8
#define COLS_PER_SPLIT (NROWS / NSPLIT)   // 2048
#define NITERS (COLS_PER_SPLIT / TILE)    // 16
#define LOG2E 1.4426950408889634f
#define C_EXP (LOG2E / 0.07f)             // a = sim*C_EXP; exp2(a) = exp(sim/T)
#define NEGBIG -1.0e30f

typedef __attribute__((ext_vector_type(8))) short bf16x8;
typedef __attribute__((ext_vector_type(4))) float f32x4;

__device__ inline unsigned short f2bf(float x) {
    unsigned int b = __float_as_uint(x);
    b += 0x7FFFu + ((b >> 16) & 1u);
    return (unsigned short)(b >> 16);
}
__device__ inline unsigned int pack2(float x, float y) {
    return (unsigned int)f2bf(x) | ((unsigned int)f2bf(y) << 16);
}

// ---------------- K1: pair-normalize -> repsB/repsA both halves; fold -mean(pos) into out ----------------
__global__ void norm_kernel(const float* __restrict__ zi, const float* __restrict__ zj,
                            unsigned short* __restrict__ repsB,
                            unsigned short* __restrict__ repsA,
                            float* __restrict__ out) {
    int w = threadIdx.x >> 6;
    int lane = threadIdx.x & 63;
    int r = blockIdx.x * 4 + w;                         // pair row 0..8191
    float2 a = ((const float2*)(zi + (size_t)r * DDIM))[lane];
    float2 b = ((const float2*)(zj + (size_t)r * DDIM))[lane];
    float si = a.x * a.x + a.y * a.y;
    float sj = b.x * b.x + b.y * b.y;
    float dj = a.x * b.x + a.y * b.y;
    #pragma unroll
    for (int d = 1; d < 64; d <<= 1) {
        si += __shfl_xor(si, d, 64);
        sj += __shfl_xor(sj, d, 64);
        dj += __shfl_xor(dj, d, 64);
    }
    float ii = 1.0f / fmaxf(sqrtf(si), 1e-12f);
    float ij = 1.0f / fmaxf(sqrtf(sj), 1e-12f);
    float xi = a.x * ii, yi = a.y * ii;
    float xj = b.x * ij, yj = b.y * ij;
    ((unsigned int*)repsB)[(size_t)r * (DDIM / 2) + lane] = pack2(xi, yi);
    ((unsigned int*)repsA)[(size_t)r * (DDIM / 2) + lane] = pack2(xi * C_EXP, yi * C_EXP);
    ((unsigned int*)repsB)[(size_t)(r + BHALF) * (DDIM / 2) + lane] = pack2(xj, yj);
    ((unsigned int*)repsA)[(size_t)(r + BHALF) * (DDIM / 2) + lane] = pack2(xj * C_EXP, yj * C_EXP);

    // pos(pair r) = exp(dot/T), appears twice in the mean (rows r and r+B)
    __shared__ float red[4];
    if (lane == 0) red[w] = __builtin_amdgcn_exp2f(dj * ii * ij * C_EXP);
    __syncthreads();
    if (threadIdx.x == 0)
        atomicAdd(out, -(red[0] + red[1] + red[2] + red[3]) * (2.0f / NROWS));
}

// ---------------- K2 tile body: global bfrag loads + MFMA + top-2 epilogue ----------------
// bt = repsB + (colTileBase + laneLo)*DDIM + quad*8  (per-lane fragment base)
template <bool DIAG>
__device__ __forceinline__ void tile_compute(const unsigned short* __restrict__ bt,
                                             const bf16x8 (&afrag)[4][4],
                                             float (&A1)[4][4], float (&A2)[4][4],
                                             int rowBase, int colBase,
                                             int laneLo, int quad) {
    #pragma unroll
    for (int c8 = 0; c8 < 8; ++c8) {
        bf16x8 bfrag[4];
        #pragma unroll
        for (int kt = 0; kt < 4; ++kt)
            bfrag[kt] = *(const bf16x8*)(bt + c8 * 16 * DDIM + kt * 32);
        #pragma unroll
        for (int rt = 0; rt < 4; ++rt) {
            f32x4 acc = (f32x4){0.f, 0.f, 0.f, 0.f};
            #pragma unroll
            for (int kt = 0; kt < 4; ++kt)
                acc = __builtin_amdgcn_mfma_f32_16x16x32_bf16(
                    afrag[rt][kt], bfrag[kt], acc, 0, 0, 0);
            #pragma unroll
            for (int rg = 0; rg < 4; ++rg) {
                float a = acc[rg];
                if (DIAG) {
                    int drel = rowBase + rt * 16 + quad * 4 + rg - colBase - laneLo;
                    a = (drel == c8 * 16) ? NEGBIG : a;
                }
                float mn = fminf(a, A1[rt][rg]);           // 3 ops/elem total
                A2[rt][rg] = fmaxf(A2[rt][rg], mn);
                A1[rt][rg] = fmaxf(A1[rt][rg], a);
            }
        }
    }
}

__global__ __launch_bounds__(256, 3)
void ntx_main(const unsigned short* __restrict__ repsA,
              const unsigned short* __restrict__ repsB,
              float2* __restrict__ part) {
    const int tid = threadIdx.x;
    const int w = tid >> 6, lane = tid & 63;
    const int laneLo = lane & 15, quad = lane >> 4;
    const int by = blockIdx.x;                          // split: linear id % 8 -> XCD-resident B panel
    const int bx = blockIdx.y;                          // row block
    const int rowBase = bx * ROWS_PER_BLOCK + w * 64;   // wave owns 64 rows

    // A fragments: 4 row-tiles x 4 k-tiles; m = lane&15, k = quad*8 + j
    bf16x8 afrag[4][4];
    #pragma unroll
    for (int rt = 0; rt < 4; ++rt)
        #pragma unroll
        for (int kt = 0; kt < 4; ++kt) {
            int r = rowBase + rt * 16 + laneLo;
            int k = kt * 32 + quad * 8;
            afrag[rt][kt] = *(const bf16x8*)(repsA + (size_t)r * DDIM + k);
        }

    float A1[4][4], A2[4][4];                           // running top-2 per lane-row
    #pragma unroll
    for (int rt = 0; rt < 4; ++rt)
        #pragma unroll
        for (int rg = 0; rg < 4; ++rg) { A1[rt][rg] = NEGBIG; A2[rt][rg] = NEGBIG; }

    const int colBase0 = by * COLS_PER_SPLIT;
    // per-lane B fragment base: row (colBase0 + laneLo), col quad*8
    const unsigned short* bp = repsB + (size_t)(colBase0 + laneLo) * DDIM + quad * 8;

    for (int it = 0; it < NITERS; ++it) {
        int colBase = colBase0 + it * TILE;
        const unsigned short* bt = bp + it * (TILE * DDIM);
        // wave's 64 rows live in one 128-aligned block -> uniform diag test
        if ((rowBase >> 7) == (colBase >> 7))
            tile_compute<true>(bt, afrag, A1, A2, rowBase, colBase, laneLo, quad);
        else
            tile_compute<false>(bt, afrag, A1, A2, rowBase, colBase, laneLo, quad);
    }

    // Merge top-2 across the 16 lanes (laneLo) sharing each row; write partials
    #pragma unroll
    for (int rt = 0; rt < 4; ++rt)
        #pragma unroll
        for (int rg = 0; rg < 4; ++rg) {
            float m1 = A1[rt][rg], m2 = A2[rt][rg];
            #pragma unroll
            for (int d = 1; d < 16; d <<= 1) {
                float m1o = __shfl_xor(m1, d, 64);
                float m2o = __shfl_xor(m2, d, 64);
                m2 = fmaxf(fmaxf(m2, m2o), fminf(m1, m1o));
                m1 = fmaxf(m1, m1o);
            }
            if (laneLo == 0) {
                int gr = rowBase + rt * 16 + quad * 4 + rg;
                part[(size_t)gr * NSPLIT + by] = make_float2(m1, m2);
            }
        }
}

// ---------------- K3: merge splits; lse = e1 + log1p(exp(e2-e1)); mean -> out ----------------
__global__ void finish_kernel(const float2* __restrict__ part,
                              float* __restrict__ out) {
    int row = blockIdx.x * 256 + threadIdx.x;           // 64 blocks x 256
    float M1 = NEGBIG, M2 = NEGBIG;
    #pragma unroll
    for (int k = 0; k < NSPLIT; ++k) {
        float2 p = part[(size_t)row * NSPLIT + k];
        M2 = fmaxf(fmaxf(M2, p.y), fminf(M1, p.x));
        M1 = fmaxf(M1, p.x);
    }
    float e1 = __builtin_amdgcn_exp2f(M1);              // top logit value
    float e2 = __builtin_amdgcn_exp2f(M2);
    float v = e1 + log1pf(__builtin_amdgcn_exp2f((e2 - e1) * LOG2E));

    #pragma unroll
    for (int d = 1; d < 64; d <<= 1) v += __shfl_xor(v, d, 64);
    __shared__ float red[4];
    int lane = threadIdx.x & 63, w = threadIdx.x >> 6;
    if (lane == 0) red[w] = v;
    __syncthreads();
    if (threadIdx.x == 0)
        atomicAdd(out, (red[0] + red[1] + red[2] + red[3]) * (1.0f / NROWS));
}

extern "C" void kernel_launch(void* const* d_in, const int* in_sizes, int n_in,
                              void* d_out, int out_size, void* d_ws, size_t ws_size,
                              hipStream_t stream) {
    const float* zi = (const float*)d_in[0];
    const float* zj = (const float*)d_in[1];
    float* out = (float*)d_out;
    unsigned short* repsB = (unsigned short*)d_ws;                              // 4 MiB
    unsigned short* repsA = repsB + (size_t)NROWS * DDIM;                       // 4 MiB
    float2* part = (float2*)((char*)d_ws + 2 * (size_t)NROWS * DDIM * 2);       // 1 MiB (total = 9 MiB, proven)

    hipMemsetAsync(out, 0, sizeof(float), stream);      // stream-ordered; graph-capturable
    norm_kernel<<<BHALF / 4, 256, 0, stream>>>(zi, zj, repsB, repsA, out);
    ntx_main<<<dim3(NSPLIT, NROWS / ROWS_PER_BLOCK), 256, 0, stream>>>(repsA, repsB, part);
    finish_kernel<<<NROWS / 256, 256, 0, stream>>>(part, out);
}

// Round 3
// 189.950 us; speedup vs baseline: 1.1443x; 1.1443x over previous
//
#include <hip/hip_runtime.h>
#include <hip/hip_bf16.h>

// NT-Xent (B=8192, D=128), top-2 formulation. R11: L2-direct B reads with
// 1-deep register ping-pong prefetch (R10 was latency-bound: loads issued
// right before use, 2 waves/SIMD, MfmaUtil 20%). Each c8-step's 4 bfrag
// loads are issued one step ahead; ~620 cyc of MFMA (2 waves/SIMD) covers
// the ~250 cyc L2 latency. B panel per split = 512 KB, XCD-resident
// (linear block id % 8 == split). Total B traffic 1.07 GB from L2 ->
// 53 B/cyc/CU at the 33 us MFMA floor vs ~56 ceiling: feasible.
// pos fused into ntx_main: the positive element sim(r, r^8192) lives in
// exactly one tile per wave (same index algebra as the diag mask, mutually
// exclusive: bit13 differs). MODE 2 captures it (not masked - it stays in
// the top-2 logits per the reference); 64 blocks atomicAdd -sum(pos)/N.
// Workspace stays at the proven 9 MiB exactly (R1 fault = pos array @9M+32K).
// Top-2 of a = sim*log2e/T (exp monotone); lse = e1 + log1p(exp(e2-e1)).
// K1: pair-normalize zi/zj -> repsB (unit) + repsA (unit*C). No atomics.
// K2: 64 row-blocks(256 rows, 4 waves x 64 rows) x 8 splits; 16 col-tiles
//     of 128; per c8: 4 prefetched loads + 16 MFMA + 3-op top-2 update.
// K3: merge 8 split partials (1 MiB) -> lse -> mean -> atomicAdd.

#define NROWS 16384
#define BHALF 8192
#define DDIM  128
#define TILE  128
#define ROWS_PER_BLOCK 256
#define NSPLIT 8
#define COLS_PER_SPLIT (NROWS / NSPLIT)   // 2048
#define NITERS (COLS_PER_SPLIT / TILE)    // 16
#define NSTEPS (NITERS * 8)               // 128 c8-steps per wave
#define STEPE  (16 * DDIM)                // elements per c8-step (16 B-rows)
#define LOG2E 1.4426950408889634f
#define C_EXP (LOG2E / 0.07f)             // a = sim*C_EXP; exp2(a) = exp(sim/T)
#define NEGBIG -1.0e30f

typedef __attribute__((ext_vector_type(8))) short bf16x8;
typedef __attribute__((ext_vector_type(4))) float f32x4;

__device__ inline unsigned short f2bf(float x) {
    unsigned int b = __float_as_uint(x);
    b += 0x7FFFu + ((b >> 16) & 1u);
    return (unsigned short)(b >> 16);
}
__device__ inline unsigned int pack2(float x, float y) {
    return (unsigned int)f2bf(x) | ((unsigned int)f2bf(y) << 16);
}

// ---------------- K1: pair-normalize -> repsB/repsA both halves ----------------
__global__ void norm_kernel(const float* __restrict__ zi, const float* __restrict__ zj,
                            unsigned short* __restrict__ repsB,
                            unsigned short* __restrict__ repsA) {
    int w = threadIdx.x >> 6;
    int lane = threadIdx.x & 63;
    int r = blockIdx.x * 4 + w;                         // pair row 0..8191
    float2 a = ((const float2*)(zi + (size_t)r * DDIM))[lane];
    float2 b = ((const float2*)(zj + (size_t)r * DDIM))[lane];
    float si = a.x * a.x + a.y * a.y;
    float sj = b.x * b.x + b.y * b.y;
    #pragma unroll
    for (int d = 1; d < 64; d <<= 1) {
        si += __shfl_xor(si, d, 64);
        sj += __shfl_xor(sj, d, 64);
    }
    float ii = 1.0f / fmaxf(sqrtf(si), 1e-12f);
    float ij = 1.0f / fmaxf(sqrtf(sj), 1e-12f);
    float xi = a.x * ii, yi = a.y * ii;
    float xj = b.x * ij, yj = b.y * ij;
    ((unsigned int*)repsB)[(size_t)r * (DDIM / 2) + lane] = pack2(xi, yi);
    ((unsigned int*)repsA)[(size_t)r * (DDIM / 2) + lane] = pack2(xi * C_EXP, yi * C_EXP);
    ((unsigned int*)repsB)[(size_t)(r + BHALF) * (DDIM / 2) + lane] = pack2(xj, yj);
    ((unsigned int*)repsA)[(size_t)(r + BHALF) * (DDIM / 2) + lane] = pack2(xj * C_EXP, yj * C_EXP);
}

// ---------------- K2 step body: 16 MFMA + top-2 epilogue ----------------
// MODE: 0 plain, 1 diag-mask, 2 pos-capture.
// specialRel = specialBase + quad*4 - colBase - laneLo (uniform pre-fold).
template <int MODE>
__device__ __forceinline__ void compute_step(const bf16x8 (&bf)[4],
                                             const bf16x8 (&afrag)[4][4],
                                             float (&A1)[4][4], float (&A2)[4][4],
                                             float (&posv)[4][4],
                                             int specialRel, int c8) {
    #pragma unroll
    for (int rt = 0; rt < 4; ++rt) {
        f32x4 acc = (f32x4){0.f, 0.f, 0.f, 0.f};
        #pragma unroll
        for (int kt = 0; kt < 4; ++kt)
            acc = __builtin_amdgcn_mfma_f32_16x16x32_bf16(
                afrag[rt][kt], bf[kt], acc, 0, 0, 0);
        #pragma unroll
        for (int rg = 0; rg < 4; ++rg) {
            float a = acc[rg];
            int drel = specialRel + rt * 16 + rg;
            if (MODE == 1) a = (drel == c8 * 16) ? NEGBIG : a;
            if (MODE == 2) posv[rt][rg] = (drel == c8 * 16) ? a : posv[rt][rg];
            float mn = fminf(a, A1[rt][rg]);            // 3 ops/elem total
            A2[rt][rg] = fmaxf(A2[rt][rg], mn);
            A1[rt][rg] = fmaxf(A1[rt][rg], a);
        }
    }
}

// One 128-col tile with ping-pong prefetch. On entry bA holds this tile's
// step 0; p points at step 1. On exit bA holds next tile's step 0; p at +1.
template <int MODE>
__device__ __forceinline__ void tile_pp(const unsigned short*& p,
                                        const unsigned short* pend,
                                        const unsigned short* pwrap,
                                        bf16x8 (&bA)[4], bf16x8 (&bB)[4],
                                        const bf16x8 (&afrag)[4][4],
                                        float (&A1)[4][4], float (&A2)[4][4],
                                        float (&posv)[4][4],
                                        int specialRel) {
    #pragma unroll
    for (int c8 = 0; c8 < 8; c8 += 2) {
        #pragma unroll
        for (int kt = 0; kt < 4; ++kt)
            bB[kt] = *(const bf16x8*)(p + kt * 32);
        p += STEPE; if (p == pend) p = pwrap;
        compute_step<MODE>(bA, afrag, A1, A2, posv, specialRel, c8);
        #pragma unroll
        for (int kt = 0; kt < 4; ++kt)
            bA[kt] = *(const bf16x8*)(p + kt * 32);
        p += STEPE; if (p == pend) p = pwrap;
        compute_step<MODE>(bB, afrag, A1, A2, posv, specialRel, c8 + 1);
    }
}

__global__ __launch_bounds__(256, 2)
void ntx_main(const unsigned short* __restrict__ repsA,
              const unsigned short* __restrict__ repsB,
              float2* __restrict__ part,
              float* __restrict__ out) {
    const int tid = threadIdx.x;
    const int w = tid >> 6, lane = tid & 63;
    const int laneLo = lane & 15, quad = lane >> 4;
    const int by = blockIdx.x;                          // split: linear id % 8 -> XCD-resident panel
    const int bx = blockIdx.y;                          // row block
    const int rowBase = bx * ROWS_PER_BLOCK + w * 64;   // wave owns 64 rows
    const int posBase = rowBase ^ BHALF;                // positive cols for these rows

    // A fragments: 4 row-tiles x 4 k-tiles; m = lane&15, k = quad*8 + j
    bf16x8 afrag[4][4];
    #pragma unroll
    for (int rt = 0; rt < 4; ++rt)
        #pragma unroll
        for (int kt = 0; kt < 4; ++kt) {
            int r = rowBase + rt * 16 + laneLo;
            int k = kt * 32 + quad * 8;
            afrag[rt][kt] = *(const bf16x8*)(repsA + (size_t)r * DDIM + k);
        }

    float A1[4][4], A2[4][4], posv[4][4];
    #pragma unroll
    for (int rt = 0; rt < 4; ++rt)
        #pragma unroll
        for (int rg = 0; rg < 4; ++rg) {
            A1[rt][rg] = NEGBIG; A2[rt][rg] = NEGBIG; posv[rt][rg] = NEGBIG;
        }

    const int colBase0 = by * COLS_PER_SPLIT;
    // per-lane B fragment base: row (colBase0 + laneLo), col quad*8
    const unsigned short* pwrap = repsB + (size_t)(colBase0 + laneLo) * DDIM + quad * 8;
    const unsigned short* pend = pwrap + (size_t)NSTEPS * STEPE;

    // Prologue: step 0 -> bA; p -> step 1
    bf16x8 bA[4], bB[4];
    #pragma unroll
    for (int kt = 0; kt < 4; ++kt)
        bA[kt] = *(const bf16x8*)(pwrap + kt * 32);
    const unsigned short* p = pwrap + STEPE;

    const int relFold = quad * 4 - laneLo;              // uniform part of drel
    for (int it = 0; it < NITERS; ++it) {
        int colBase = colBase0 + it * TILE;
        if ((rowBase >> 7) == (colBase >> 7))
            tile_pp<1>(p, pend, pwrap, bA, bB, afrag, A1, A2, posv,
                       rowBase - colBase + relFold);
        else if ((posBase >> 7) == (colBase >> 7))
            tile_pp<2>(p, pend, pwrap, bA, bB, afrag, A1, A2, posv,
                       posBase - colBase + relFold);
        else
            tile_pp<0>(p, pend, pwrap, bA, bB, afrag, A1, A2, posv, 0x7FFFFFF);
    }

    // Merge top-2 across the 16 lanes (laneLo) sharing each row; write partials
    #pragma unroll
    for (int rt = 0; rt < 4; ++rt)
        #pragma unroll
        for (int rg = 0; rg < 4; ++rg) {
            float m1 = A1[rt][rg], m2 = A2[rt][rg];
            #pragma unroll
            for (int d = 1; d < 16; d <<= 1) {
                float m1o = __shfl_xor(m1, d, 64);
                float m2o = __shfl_xor(m2, d, 64);
                m2 = fmaxf(fmaxf(m2, m2o), fminf(m1, m1o));
                m1 = fmaxf(m1, m1o);
            }
            if (laneLo == 0) {
                int gr = rowBase + rt * 16 + quad * 4 + rg;
                part[(size_t)gr * NSPLIT + by] = make_float2(m1, m2);
            }
        }

    // pos: this wave saw its positive tile iff posBase is inside this split.
    if ((posBase >> 11) == by) {
        float s = 0.0f;
        #pragma unroll
        for (int rt = 0; rt < 4; ++rt)
            #pragma unroll
            for (int rg = 0; rg < 4; ++rg) {
                float pv = posv[rt][rg];
                #pragma unroll
                for (int d = 1; d < 16; d <<= 1)
                    pv = fmaxf(pv, __shfl_xor(pv, d, 64));
                s += __builtin_amdgcn_exp2f(pv);        // exp2(NEGBIG)=0 safety
            }
        s += __shfl_xor(s, 16, 64);                     // reduce across quads
        s += __shfl_xor(s, 32, 64);
        if (lane == 0) atomicAdd(out, -s * (1.0f / NROWS));
    }
}

// ---------------- K3: merge splits; lse = e1 + log1p(exp(e2-e1)); mean -> out ----------------
__global__ void finish_kernel(const float2* __restrict__ part,
                              float* __restrict__ out) {
    int row = blockIdx.x * 256 + threadIdx.x;           // 64 blocks x 256
    float M1 = NEGBIG, M2 = NEGBIG;
    #pragma unroll
    for (int k = 0; k < NSPLIT; ++k) {
        float2 p = part[(size_t)row * NSPLIT + k];
        M2 = fmaxf(fmaxf(M2, p.y), fminf(M1, p.x));
        M1 = fmaxf(M1, p.x);
    }
    float e1 = __builtin_amdgcn_exp2f(M1);              // top logit value
    float e2 = __builtin_amdgcn_exp2f(M2);
    float v = e1 + log1pf(__builtin_amdgcn_exp2f((e2 - e1) * LOG2E));

    #pragma unroll
    for (int d = 1; d < 64; d <<= 1) v += __shfl_xor(v, d, 64);
    __shared__ float red[4];
    int lane = threadIdx.x & 63, w = threadIdx.x >> 6;
    if (lane == 0) red[w] = v;
    __syncthreads();
    if (threadIdx.x == 0)
        atomicAdd(out, (red[0] + red[1] + red[2] + red[3]) * (1.0f / NROWS));
}

extern "C" void kernel_launch(void* const* d_in, const int* in_sizes, int n_in,
                              void* d_out, int out_size, void* d_ws, size_t ws_size,
                              hipStream_t stream) {
    const float* zi = (const float*)d_in[0];
    const float* zj = (const float*)d_in[1];
    float* out = (float*)d_out;
    unsigned short* repsB = (unsigned short*)d_ws;                              // 4 MiB
    unsigned short* repsA = repsB + (size_t)NROWS * DDIM;                       // 4 MiB
    float2* part = (float2*)((char*)d_ws + 2 * (size_t)NROWS * DDIM * 2);       // 1 MiB (total 9 MiB)

    hipMemsetAsync(out, 0, sizeof(float), stream);      // stream-ordered; graph-capturable
    norm_kernel<<<BHALF / 4, 256, 0, stream>>>(zi, zj, repsB, repsA);
    ntx_main<<<dim3(NSPLIT, NROWS / ROWS_PER_BLOCK), 256, 0, stream>>>(repsA, repsB, part, out);
    finish_kernel<<<NROWS / 256, 256, 0, stream>>>(part, out);
}